// Round 9
// baseline (84.136 us; speedup 1.0000x reference)
//
#include <hip/hip_runtime.h>
#include <hip/hip_bf16.h>
#include <cstddef>

// MoE gate: B,S,D,E,K = 4,4096,2048,64,2. N = 16384 tokens.
// out layout: dispatch [N][E][K] (2,097,152 f) | combine [N][E][K] | lbl | z
namespace {
constexpr int kD = 2048;
constexpr int kE = 64;
constexpr int kN = 16384;
constexpr size_t kDispatchFloats = (size_t)kN * kE * 2;  // 2,097,152
}

typedef short short8_t __attribute__((ext_vector_type(8)));
typedef float f32x4 __attribute__((ext_vector_type(4)));

// ---------------------------------------------------------------------------
__global__ void zero_ws_kernel(float* __restrict__ ws) {
  ws[threadIdx.x] = 0.0f;  // 256 accumulator slots (129 used)
}

// fp32 -> 3 scaled bf16 splits: x ~= s1 + s2*2^-8 + s3*2^-16 (all normal bf16)
__device__ __forceinline__ void split3(float f, unsigned short& s1,
                                       unsigned short& s2, unsigned short& s3) {
  __hip_bfloat16 h1 = __float2bfloat16(f);
  float r1 = (f - __bfloat162float(h1)) * 256.0f;
  __hip_bfloat16 h2 = __float2bfloat16(r1);
  float r2 = (r1 - __bfloat162float(h2)) * 256.0f;
  __hip_bfloat16 h3 = __float2bfloat16(r2);
  s1 = __builtin_bit_cast(unsigned short, h1);
  s2 = __builtin_bit_cast(unsigned short, h2);
  s3 = __builtin_bit_cast(unsigned short, h3);
}

// convert 16 floats (4x float4) -> 3 splits, store swizzled 16B cols into tile
__device__ __forceinline__ void conv_store(const float4* v,
                                           unsigned short (*dst)[64][64],
                                           int srow, int seg) {
  short8_t o1[2], o2[2], o3[2];
#pragma unroll
  for (int j = 0; j < 4; ++j) {
    const float4 f = v[j];
    const int ch = j >> 1, b0 = (j & 1) * 4;
    unsigned short s1, s2, s3;
    split3(f.x, s1, s2, s3); o1[ch][b0+0]=(short)s1; o2[ch][b0+0]=(short)s2; o3[ch][b0+0]=(short)s3;
    split3(f.y, s1, s2, s3); o1[ch][b0+1]=(short)s1; o2[ch][b0+1]=(short)s2; o3[ch][b0+1]=(short)s3;
    split3(f.z, s1, s2, s3); o1[ch][b0+2]=(short)s1; o2[ch][b0+2]=(short)s2; o3[ch][b0+2]=(short)s3;
    split3(f.w, s1, s2, s3); o1[ch][b0+3]=(short)s1; o2[ch][b0+3]=(short)s2; o3[ch][b0+3]=(short)s3;
  }
#pragma unroll
  for (int ch = 0; ch < 2; ++ch) {
    const int col = (seg * 2 + ch) ^ (srow & 7);
    *reinterpret_cast<short8_t*>(&dst[0][srow][col * 8]) = o1[ch];
    *reinterpret_cast<short8_t*>(&dst[1][srow][col * 8]) = o2[ch];
    *reinterpret_cast<short8_t*>(&dst[2][srow][col * 8]) = o3[ch];
  }
}

// ---------------------------------------------------------------------------
// Fused kernel: 256 blocks x 512 thr (8 waves). Block = 64 tokens, full K.
// wave wv: kh = wv>>2 (K-half of 1024), wr = (wv>>1)&1 (token half),
// wc = wv&1 (expert half). Each K-half has its own 48KB LDS tile set; 16
// BK=64 chunks per half; register prefetch of chunk c+1 issued before the
// MFMA of chunk c (HBM latency hides under compute). K-halves merge via
// commutative LDS float atomics (bitwise-deterministic: 0+a+b == 0+b+a).
// Then in-block softmax/top-2/outputs/losses (r6-proven gate code).
__global__ __launch_bounds__(512)
void moe_fused_kernel(const float* __restrict__ x, const float* __restrict__ W,
                      float* __restrict__ out, float* __restrict__ ws) {
  __shared__ unsigned short xs[2][3][64][64];  // [kh][split][tok][k] 48KB x2
  __shared__ unsigned short wh[2][3][64][64];  // [kh][split][exp][k] (with xs: 96KB)
  __shared__ float lg[64][65];                 // logits, 16.6KB
  __shared__ int ti0[64], ti1[64];
  __shared__ float tv0[64], tv1[64], tz2[64];

  const int tid  = threadIdx.x;
  const int lane = tid & 63;
  const int wv   = __builtin_amdgcn_readfirstlane(tid >> 6);
  const int kh   = wv >> 2;
  const int wr   = (wv >> 1) & 1;
  const int wc   = wv & 1;
  const int tile = blockIdx.x;
  const int lrow = lane & 15;
  const int lk   = lane >> 4;

  // staging role: half kh staged by tids [kh*256, +256); 4 thr/row, 16 floats
  const int h = tid & 255;
  const int srow = h >> 2, seg = h & 3;
  const float4* __restrict__ bx = reinterpret_cast<const float4*>(x) +
      ((size_t)tile * 64 + srow) * 512 + kh * 256 + seg * 4;
  const float4* __restrict__ bw = reinterpret_cast<const float4*>(W) +
      (size_t)srow * 512 + kh * 256 + seg * 4;

  // zero the logits tile (atomic-add target)
  {
    float* lgf = &lg[0][0];
    for (int i = tid; i < 64 * 65; i += 512) lgf[i] = 0.0f;
  }

  f32x4 acc0[2][2], acc1[2][2], acc2[2][2];
  const f32x4 z4 = {0.0f, 0.0f, 0.0f, 0.0f};
#pragma unroll
  for (int a = 0; a < 2; ++a)
#pragma unroll
    for (int b = 0; b < 2; ++b) { acc0[a][b] = z4; acc1[a][b] = z4; acc2[a][b] = z4; }

  // prologue: stage chunk 0
  float4 vx[4], vw[4];
#pragma unroll
  for (int j = 0; j < 4; ++j) vx[j] = bx[j];
#pragma unroll
  for (int j = 0; j < 4; ++j) vw[j] = bw[j];
  conv_store(vx, xs[kh], srow, seg);
  conv_store(vw, wh[kh], srow, seg);
  __syncthreads();

  for (int c = 0; c < 16; ++c) {
    if (c < 15) {  // issue next chunk's loads; in flight during MFMA phase
#pragma unroll
      for (int j = 0; j < 4; ++j) vx[j] = bx[(c + 1) * 16 + j];
#pragma unroll
      for (int j = 0; j < 4; ++j) vw[j] = bw[(c + 1) * 16 + j];
    }
    // MFMA on chunk c
#pragma unroll
    for (int ks = 0; ks < 2; ++ks) {
      const int kc = ks * 4 + lk;
      short8_t a1[2], a2[2], a3[2], b1[2], b2[2], b3[2];
#pragma unroll
      for (int mt = 0; mt < 2; ++mt) {
        const int r = wr * 32 + mt * 16 + lrow;
        const int cw = (kc ^ (r & 7)) * 8;
        a1[mt] = *reinterpret_cast<const short8_t*>(&xs[kh][0][r][cw]);
        a2[mt] = *reinterpret_cast<const short8_t*>(&xs[kh][1][r][cw]);
        a3[mt] = *reinterpret_cast<const short8_t*>(&xs[kh][2][r][cw]);
      }
#pragma unroll
      for (int nt = 0; nt < 2; ++nt) {
        const int e = wc * 32 + nt * 16 + lrow;
        const int cw = (kc ^ (e & 7)) * 8;
        b1[nt] = *reinterpret_cast<const short8_t*>(&wh[kh][0][e][cw]);
        b2[nt] = *reinterpret_cast<const short8_t*>(&wh[kh][1][e][cw]);
        b3[nt] = *reinterpret_cast<const short8_t*>(&wh[kh][2][e][cw]);
      }
#pragma unroll
      for (int mt = 0; mt < 2; ++mt)
#pragma unroll
        for (int nt = 0; nt < 2; ++nt) {
          acc0[mt][nt] = __builtin_amdgcn_mfma_f32_16x16x32_bf16(a1[mt], b1[nt], acc0[mt][nt], 0, 0, 0);
          acc1[mt][nt] = __builtin_amdgcn_mfma_f32_16x16x32_bf16(a1[mt], b2[nt], acc1[mt][nt], 0, 0, 0);
          acc1[mt][nt] = __builtin_amdgcn_mfma_f32_16x16x32_bf16(a2[mt], b1[nt], acc1[mt][nt], 0, 0, 0);
          acc2[mt][nt] = __builtin_amdgcn_mfma_f32_16x16x32_bf16(a1[mt], b3[nt], acc2[mt][nt], 0, 0, 0);
          acc2[mt][nt] = __builtin_amdgcn_mfma_f32_16x16x32_bf16(a3[mt], b1[nt], acc2[mt][nt], 0, 0, 0);
          acc2[mt][nt] = __builtin_amdgcn_mfma_f32_16x16x32_bf16(a2[mt], b2[nt], acc2[mt][nt], 0, 0, 0);
        }
    }
    __syncthreads();                 // all waves done reading this chunk
    if (c < 15) {
      conv_store(vx, xs[kh], srow, seg);   // waits vmcnt here, not earlier
      conv_store(vw, wh[kh], srow, seg);
    }
    __syncthreads();                 // next chunk ready
  }

  // merge K-halves into lg via commutative LDS atomics
  const float k8 = 1.0f / 256.0f, k16 = 1.0f / 65536.0f;
#pragma unroll
  for (int mt = 0; mt < 2; ++mt)
#pragma unroll
    for (int nt = 0; nt < 2; ++nt)
#pragma unroll
      for (int r = 0; r < 4; ++r) {
        const float v = acc0[mt][nt][r] + acc1[mt][nt][r] * k8 + acc2[mt][nt][r] * k16;
        atomicAdd(&lg[wr * 32 + mt * 16 + lk * 4 + r][wc * 32 + nt * 16 + lrow], v);
      }
  __syncthreads();

  // --- gate phase (r6-proven): softmax + top-2 + z-loss, wave 0 ------------
  if (tid < 64) {
    float v0 = -INFINITY, v1 = -INFINITY;
    int i0 = 0, i1 = 0;
    for (int e = 0; e < kE; ++e) {
      const float l = lg[tid][e];
      if (l > v0) { v1 = v0; i1 = i0; v0 = l; i0 = e; }
      else if (l > v1) { v1 = l; i1 = e; }
    }
    const float m = v0;
    float s = 0.0f;
    for (int e = 0; e < kE; ++e) s += __expf(lg[tid][e] - m);
    const float rs = 1.0f / s;
    float zexp = 0.0f;
    for (int e = 0; e < kE; ++e) zexp += __expf(__expf(lg[tid][e] - m) * rs);
    const float z = logf(zexp);
    ti0[tid] = i0; ti1[tid] = i1;
    tv0[tid] = rs;                    // exp(v0-m)*rs with v0==m
    tv1[tid] = __expf(v1 - m) * rs;
    tz2[tid] = z * z;
  }
  __syncthreads();

  // losses: thread = expert, deterministic in-block order; 256 atomics/address
  if (tid < kE) {
    float g = 0.0f, cnt = 0.0f;
    for (int t = 0; t < 64; ++t) {
      if (ti0[t] == tid) { g += tv0[t]; cnt += 1.0f; }
      if (ti1[t] == tid) { g += tv1[t]; cnt += 1.0f; }
    }
    atomicAdd(&ws[tid], g);
    atomicAdd(&ws[kE + tid], cnt);
    float z2 = tz2[tid];
    for (int off = 32; off; off >>= 1) z2 += __shfl_down(z2, off);
    if (tid == 0) atomicAdd(&ws[2 * kE], z2);
  }

  // outputs: 8 threads per token, 4 float4 per tensor each, coalesced
  {
    const int t = tid >> 3, sub = tid & 7;
    const int i0 = ti0[t], i1 = ti1[t];
    const float v0 = tv0[t], v1 = tv1[t];
    float4* __restrict__ dp =
        reinterpret_cast<float4*>(out) + ((size_t)tile * 64 + t) * 32;
    float4* __restrict__ cp =
        reinterpret_cast<float4*>(out) + (size_t)kN * 32 + ((size_t)tile * 64 + t) * 32;
#pragma unroll
    for (int j = 0; j < 4; ++j) {
      const int qq = sub * 4 + j;
      const int e0 = qq * 2, e1 = qq * 2 + 1;
      const float d0v = (e0 == i0 || e0 == i1) ? 1.0f : 0.0f;
      const float d1v = (e1 == i0 || e1 == i1) ? 1.0f : 0.0f;
      const float c0 = (e0 == i0) ? v0 : ((e0 == i1) ? v1 : 0.0f);
      const float c1 = (e1 == i0) ? v0 : ((e1 == i1) ? v1 : 0.0f);
      dp[qq] = make_float4(d0v, 0.0f, d1v, 0.0f);
      cp[qq] = make_float4(c0, 0.0f, c1, 0.0f);
    }
  }
}

// ---------------------------------------------------------------------------
__global__ void finalize_kernel(const float* __restrict__ ws,
                                float* __restrict__ out) {
  const int e = threadIdx.x;  // 64 threads
  float prod = ws[e] * ws[kE + e];
  for (int off = 32; off; off >>= 1) prod += __shfl_down(prod, off);
  if (e == 0) {
    const size_t base = kDispatchFloats * 2;
    const float invN = 1.0f / (float)kN;
    out[base]     = prod * ((float)kE * invN * invN);  // load_balancing_loss
    out[base + 1] = ws[2 * kE] * invN;                 // router_z_loss
  }
}

// ---------------------------------------------------------------------------
extern "C" void kernel_launch(void* const* d_in, const int* in_sizes, int n_in,
                              void* d_out, int out_size, void* d_ws,
                              size_t ws_size, hipStream_t stream) {
  const float* x = (const float*)d_in[0];  // [4,4096,2048] fp32
  const float* W = (const float*)d_in[1];  // [64,2048] fp32
  float* out = (float*)d_out;
  float* ws = (float*)d_ws;

  zero_ws_kernel<<<1, 256, 0, stream>>>(ws);
  moe_fused_kernel<<<256, 512, 0, stream>>>(x, W, out, ws);
  finalize_kernel<<<1, kE, 0, stream>>>(ws, out);
}